// Round 6
// baseline (333.665 us; speedup 1.0000x reference)
//
#include <hip/hip_runtime.h>
#include <hip/hip_cooperative_groups.h>
#include <cstdint>
#include <cstddef>

namespace cg = cooperative_groups;

// CPDLoss (SSD MultiBox-style): B=8, A=131072, M=64.
// R6: ONE cooperative kernel (R5 structure) with the P4 residual bug fixed:
// the k2*binfloor residual is now added ONCE (tid==0, post-reduction), not by
// all 512 threads. Phases: P0 zero ws -> P1 match -> P2 losses+h1 -> P3 h2
// -> P4 per-batch negative select sum -> P5 output.

#define A_N 131072
#define B_N 8
#define M_N 64
#define OVTH 0.5f
#define VAR0 0.1f
#define CNT_SH 46
#define SUM_MASK ((1ull << CNT_SH) - 1ull)
#define FIXF 1048576.0f
#define INV_FIX (1.0 / 1048576.0)
#define ZWORDS 33296   // zero-init: scalars+numpos+lcn+bpi+h1+h2 (u64 words)

static __device__ __forceinline__ unsigned long long packCE(float ce) {
  return (1ull << CNT_SH) | (unsigned long long)(ce * FIXF + 0.5f);
}

// 512-thread block radix-bin finder over 2048 packed-u64 bins.
// Finds bin t with (above < k <= above+cnt[t]); outAb = count strictly above t.
static __device__ void findBin512(const unsigned long long* __restrict__ h,
                                  unsigned int k, unsigned int* scanBuf,
                                  int* outT, unsigned int* outAb)
{
  const int tid = threadIdx.x;
  unsigned int c[4];
  unsigned int ps = 0;
  #pragma unroll
  for (int j = 0; j < 4; ++j) {
    c[j] = (unsigned int)(h[tid * 4 + j] >> CNT_SH);
    ps += c[j];
  }
  scanBuf[tid] = ps;
  __syncthreads();
  unsigned int v = ps;
  for (int off = 1; off < 512; off <<= 1) {
    unsigned int u = (tid + off < 512) ? scanBuf[tid + off] : 0u;
    __syncthreads();
    v += u;
    scanBuf[tid] = v;
    __syncthreads();
  }
  unsigned int above = v - ps;   // suffix sum of chunks strictly above this one
  #pragma unroll
  for (int j = 3; j >= 0; --j) {
    unsigned int cj = c[j];
    if (above < k && above + cj >= k) { *outT = tid * 4 + j; *outAb = above; }
    above += cj;
  }
  __syncthreads();
}

__launch_bounds__(512, 4)
__global__ void k_fused(const float4* __restrict__ anchors,
                        const float*  __restrict__ targets,
                        const float2* __restrict__ loc_pred,
                        const float2* __restrict__ conf_pred,
                        unsigned long long* __restrict__ ws64,
                        float* __restrict__ out)
{
  // workspace map (u64 units)
  double* lossL  = (double*)(ws64 + 0);
  double* lossCp = (double*)(ws64 + 1);
  unsigned int* numpos = (unsigned int*)(ws64 + 2);   // [8]
  double* lcn = (double*)(ws64 + 8);                  // [8]
  unsigned long long* bpi = ws64 + 16;                // [512]
  unsigned long long* h1  = ws64 + 528;               // [8*2048]
  unsigned long long* h2  = ws64 + 16912;             // [8*2048]

  // LDS (single block footprint ~34 KB; 2 blocks/CU)
  __shared__ float4 sTB[M_N];           // targets by original m
  __shared__ float4 sBX[M_N];           // compacted valid boxes
  __shared__ float  sBA[M_N];
  __shared__ int    sBM[M_N];
  __shared__ int    sNV;
  __shared__ unsigned long long sKey[M_N][8];
  __shared__ int    ovTab[2048];
  __shared__ unsigned long long hh[2048];
  __shared__ unsigned int scanBuf[512];
  __shared__ int sT; __shared__ unsigned int sAb;
  __shared__ double rL[8], rC[8];
  __shared__ unsigned int rN[8];

  cg::grid_group grid = cg::this_grid();
  const int tid  = threadIdx.x;
  const int wave = tid >> 6, lane = tid & 63;
  const int blk  = blockIdx.x;
  const int b    = blk >> 6;      // batch
  const int xb   = blk & 63;      // chunk within batch
  const int base = xb * 2048;     // first anchor of this block's range

  // ---------------- P0: zero workspace (poisoned 0xAA each iteration) -------
  {
    unsigned int gi = (unsigned int)blk * 512u + tid;
    if (gi < ZWORDS) ws64[gi] = 0ull;
  }

  // ---------------- P1 prep: load targets, compact valid truths -------------
  sKey[tid >> 3][tid & 7] = 0ull;
  if (tid < M_N) {
    const float* t = targets + ((size_t)b * M_N + tid) * 5;
    float x1 = t[0], y1 = t[1], x2 = t[2], y2 = t[3], lab = t[4];
    sTB[tid] = make_float4(x1, y1, x2, y2);
    bool valid = lab > 0.f;
    unsigned long long mask = __ballot(valid);
    int pfx = __popcll(mask & ((1ull << tid) - 1ull));
    if (valid) {
      sBX[pfx] = make_float4(x1, y1, x2, y2);
      sBA[pfx] = (x2 - x1) * (y2 - y1);
      sBM[pfx] = tid;
    }
    if (tid == 0) sNV = (int)__popcll(mask);
  }
  grid.sync();   // P0 zeros visible; LDS prep done

  // ---------------- P1: match ----------------------------------------------
  const int nv = sNV;
  float ax1[4], ay1[4], ax2[4], ay2[4], sa[4];
  float bv[4]; int bm[4];
  #pragma unroll
  for (int i = 0; i < 4; ++i) {
    float4 an = anchors[base + tid + i * 512];
    ax1[i] = an.x - an.z * 0.5f; ay1[i] = an.y - an.w * 0.5f;
    ax2[i] = an.x + an.z * 0.5f; ay2[i] = an.y + an.w * 0.5f;
    sa[i] = (ax2[i] - ax1[i]) * (ay2[i] - ay1[i]);
    bv[i] = -1.0f; bm[i] = 0;   // invalid rows (-1) never beat valid q>=0
  }
  #pragma unroll 2
  for (int j = 0; j < nv; ++j) {
    float4 t = sBX[j];
    float ta = sBA[j];
    int mm = sBM[j];
    float lb = -1.0f; int li = 0;
    #pragma unroll
    for (int i = 0; i < 4; ++i) {
      float wx = fminf(ax2[i], t.z) - fmaxf(ax1[i], t.x);
      float wy = fminf(ay2[i], t.w) - fmaxf(ay1[i], t.y);
      float inter = fmaxf(wx, 0.f) * fmaxf(wy, 0.f);
      float uni = (sa[i] + ta) - inter;
      float q = inter * __builtin_amdgcn_rcpf(uni);
      if (q > bv[i]) { bv[i] = q; bm[i] = mm; }     // strict >: np first-max
      if (q > lb) { lb = q; li = i; }
    }
    float wm = lb;
    #pragma unroll
    for (int off = 32; off; off >>= 1) wm = fmaxf(wm, __shfl_xor(wm, off));
    unsigned long long msk = __ballot(lb == wm);
    int lead = __ffsll((unsigned long long)msk) - 1;
    int wi = __shfl(li, lead);
    if (lane == 0) {
      int aw = base + wave * 64 + lead + wi * 512;
      sKey[mm][wave] = ((unsigned long long)__float_as_uint(wm) << 32) |
                       (unsigned long long)(0x7FFFFFFFu - (unsigned)aw);
    }
  }
  __syncthreads();
  if (tid < M_N) {
    unsigned long long k0 = sKey[tid][0];
    #pragma unroll
    for (int w = 1; w < 8; ++w) {
      unsigned long long k2 = sKey[tid][w];
      k0 = (k2 > k0) ? k2 : k0;
    }
    if (k0) atomicMax(bpi + b * M_N + tid, k0);
  }
  grid.sync();

  // ---------------- P2: override + CE + losses + level-1 histogram ----------
  for (int j = tid; j < 2048; j += 512) { ovTab[j] = -1; hh[j] = 0ull; }
  __syncthreads();
  if (tid < M_N) {
    unsigned long long key = bpi[b * M_N + tid];
    if (key) {
      int a = (int)(0x7FFFFFFFu - (unsigned)(key & 0xFFFFFFFFull));
      int loc = a - base;
      if (loc >= 0 && loc < 2048) atomicMax(&ovTab[loc], tid);  // max m = last-write-wins
    }
  }
  __syncthreads();
  double lL = 0.0, lC = 0.0;
  unsigned int npc = 0;
  unsigned int bits[4];
  #pragma unroll
  for (int i = 0; i < 4; ++i) {
    const int local = tid + i * 512;
    const int a = base + local;
    const size_t g = (size_t)b * A_N + a;
    int movr = ovTab[local];
    bool conf = (bv[i] >= OVTH) || (movr >= 0);
    int idx = (movr >= 0) ? movr : bm[i];
    float2 cp = conf_pred[g];
    float mx = fmaxf(cp.x, cp.y), mn = fminf(cp.x, cp.y);
    float ce = (mx + log1pf(expf(mn - mx))) - (conf ? cp.y : cp.x);
    bits[i] = 0u;
    if (conf) {
      npc++; lC += (double)ce;
      float4 t = sTB[idx];
      float4 an = anchors[a];
      float gx = ((t.x + t.z) * 0.5f - an.x) / (VAR0 * an.z);
      float gy = ((t.y + t.w) * 0.5f - an.y) / (VAR0 * an.w);
      float2 lp = loc_pred[g];
      float dx = fabsf(lp.x - gx), dy = fabsf(lp.y - gy);
      lL += (double)((dx < 1.f ? 0.5f * dx * dx : dx - 0.5f) +
                     (dy < 1.f ? 0.5f * dy * dy : dy - 0.5f));
    } else {
      bits[i] = __float_as_uint(ce);    // ce > 0 -> monotone, nonzero
      atomicAdd(&hh[bits[i] >> 21], packCE(ce));
    }
  }
  __syncthreads();
  for (int j = tid; j < 2048; j += 512) {
    unsigned long long v = hh[j];
    if (v) atomicAdd(&h1[(size_t)b * 2048 + j], v);
  }
  for (int off = 32; off; off >>= 1) {
    lL += __shfl_down(lL, off);
    lC += __shfl_down(lC, off);
    npc += __shfl_down(npc, off);
  }
  if (lane == 0) { rL[wave] = lL; rC[wave] = lC; rN[wave] = npc; }
  __syncthreads();
  if (tid == 0) {
    double aL = 0, aC = 0; unsigned int n = 0;
    #pragma unroll
    for (int w = 0; w < 8; ++w) { aL += rL[w]; aC += rC[w]; n += rN[w]; }
    if (aL != 0.0) atomicAdd(lossL, aL);
    if (aC != 0.0) atomicAdd(lossCp, aC);
    if (n) atomicAdd(numpos + b, n);
  }
  grid.sync();

  // ---------------- P3: level-2 histogram (bin t1 refinement) ---------------
  {
    const unsigned int P = numpos[b];
    const unsigned int k = min(3u * P, (unsigned)A_N - P);
    if (k > 0u) {
      findBin512(h1 + (size_t)b * 2048, k, scanBuf, &sT, &sAb);
      const int t1 = sT;
      for (int j = tid; j < 2048; j += 512) hh[j] = 0ull;
      __syncthreads();
      #pragma unroll
      for (int i = 0; i < 4; ++i) {
        unsigned int x = bits[i];
        if (x && (int)(x >> 21) == t1)
          atomicAdd(&hh[(x >> 10) & 2047], packCE(__uint_as_float(x)));
      }
      __syncthreads();
      for (int j = tid; j < 2048; j += 512) {
        unsigned long long v = hh[j];
        if (v) atomicAdd(&h2[(size_t)b * 2048 + j], v);
      }
    }
  }
  grid.sync();

  // ---------------- P4: per-batch negative-CE sum (8 blocks) ----------------
  if (xb == 0) {
    const unsigned int P = numpos[b];
    const unsigned int k = min(3u * P, (unsigned)A_N - P);
    if (k > 0u) {
      findBin512(h1 + (size_t)b * 2048, k, scanBuf, &sT, &sAb);
      const int t1 = sT; const unsigned int k1 = k - sAb;
      findBin512(h2 + (size_t)b * 2048, k1, scanBuf, &sT, &sAb);
      const int t2 = sT; const unsigned int k2 = k1 - sAb;
      double sfix = 0.0;
      for (int j = tid; j < 2048; j += 512) {
        if (j > t1) sfix += (double)(h1[(size_t)b * 2048 + j] & SUM_MASK);
        if (j > t2) sfix += (double)(h2[(size_t)b * 2048 + j] & SUM_MASK);
      }
      double s = sfix * INV_FIX;
      for (int off = 32; off; off >>= 1) s += __shfl_down(s, off);
      if (lane == 0) rL[wave] = s;
      __syncthreads();
      if (tid == 0) {
        double tot = 0;
        #pragma unroll
        for (int w = 0; w < 8; ++w) tot += rL[w];
        // residual ONCE: k2 entries inside bin (t1,t2) at the bin floor value
        // (under-estimate <= k2 * v * 2^-13 -- negligible vs threshold).
        // R5 bug: this was added per-thread (512x) before the reduction.
        tot += (double)k2 * (double)__uint_as_float(
                   (((unsigned)t1 << 21) | ((unsigned)t2 << 10)));
        lcn[b] = tot;
      }
    }
  }
  grid.sync();

  // ---------------- P5: final output ----------------------------------------
  if (blk == 0 && tid == 0) {
    double ll = *lossL, lcp = *lossCp, lcnt = 0;
    unsigned int tot = 0;
    #pragma unroll
    for (int i = 0; i < B_N; ++i) { tot += numpos[i]; lcnt += lcn[i]; }
    double tn = (double)tot;
    out[0] = (float)(ll / tn);
    out[1] = (float)((lcp + lcnt) / tn);
  }
}

// -------------------------------------------------------------------- launcher
extern "C" void kernel_launch(void* const* d_in, const int* in_sizes, int n_in,
                              void* d_out, int out_size, void* d_ws, size_t ws_size,
                              hipStream_t stream)
{
  const float2* loc     = (const float2*)d_in[0];  // (B,A,2)
  const float2* confp   = (const float2*)d_in[1];  // (B,A,2)
  const float4* anchors = (const float4*)d_in[2];  // (A,4)
  const float*  targets = (const float*)d_in[3];   // (B,M,5)
  unsigned long long* ws64 = (unsigned long long*)d_ws;
  float* out = (float*)d_out;

  void* args[] = { (void*)&anchors, (void*)&targets, (void*)&loc,
                   (void*)&confp, (void*)&ws64, (void*)&out };
  hipLaunchCooperativeKernel((const void*)k_fused, dim3(512), dim3(512),
                             args, 0, stream);
}

// Round 7
// 131.357 us; speedup vs baseline: 2.5401x; 2.5401x over previous
//
#include <hip/hip_runtime.h>
#include <cstdint>
#include <cstddef>

// CPDLoss (SSD MultiBox-style): B=8, A=131072, M=64.
// R7: back to multi-dispatch (R6 showed grid.sync ~40-50us each on MI355X).
// memset(266KB) -> k_match (match + ALL losses assuming no override + h1 +
// ceBits + matchOut) -> k_fix (1 block: patch the <=512 forced anchors into
// the aggregates) -> k_sel2 (level-2 hist) -> k_final (2-level select +
// residual, proven exact-enough in R6 with absmax 0.0).

#define A_N 131072
#define B_N 8
#define M_N 64
#define OVTH 0.5f
#define VAR0 0.1f
#define CNT_SH 46
#define SUM_MASK ((1ull << CNT_SH) - 1ull)
#define FIXF 1048576.0f
#define INV_FIX (1.0 / 1048576.0)
// ws u64-word map: 0 lossL | 1 lossCp | 2..5 numpos[8] u32 | 6 lossCn | 7 ticket
//                  16 bpi[512] | 528 h1[8*2048] | 16912 h2[8*2048]
#define W_BPI 16
#define W_H1  528
#define W_H2  16912
#define ZWORDS 33296
#define ZBYTES (ZWORDS * 8)

static __device__ __forceinline__ unsigned long long packCE(float ce) {
  return (1ull << CNT_SH) | (unsigned long long)(ce * FIXF + 0.5f);
}
static __device__ __forceinline__ float sl1(float d) {
  return d < 1.f ? 0.5f * d * d : d - 0.5f;
}

// ---------------------------------------------------------------- match+loss
// 512 thr/block, 4 anchors/thread (stride 512), grid (64,8).
// Phase A: compact valid truths (ballot prefix) into LDS.
// Phase B: per valid truth: 4 IoU (rcp), per-anchor strict-> (np first-max),
//          f32 max butterfly + lowest-lane tie -> per-wave u64 key.
// Phase C: losses assuming NO override: conf = bv>=0.5; CE; positives ->
//          lossL/lossCp/numpos; negatives -> ceBits + h1 (LDS u64 packed).
// Phase D: flush hh->h1, reductions, sKey->bpi atomicMax.
__launch_bounds__(512, 4)
__global__ void k_match(const float4* __restrict__ anchors,
                        const float*  __restrict__ targets,
                        const float2* __restrict__ loc_pred,
                        const float2* __restrict__ conf_pred,
                        unsigned long long* __restrict__ ws64,
                        unsigned char* __restrict__ matchOut,
                        unsigned int* __restrict__ ceBits)
{
  double* lossL  = (double*)(ws64 + 0);
  double* lossCp = (double*)(ws64 + 1);
  unsigned int* numpos = (unsigned int*)(ws64 + 2);
  unsigned long long* bpi = ws64 + W_BPI;
  unsigned long long* h1  = ws64 + W_H1;

  __shared__ float4 sTB[M_N];
  __shared__ float4 sBX[M_N];
  __shared__ float  sBA[M_N];
  __shared__ int    sBM[M_N];
  __shared__ int    sNV;
  __shared__ unsigned long long sKey[M_N][8];
  __shared__ unsigned long long hh[2048];
  __shared__ double rL[8], rC[8];
  __shared__ unsigned int rN[8];

  const int tid = threadIdx.x;
  const int wave = tid >> 6, lane = tid & 63;
  const int b = blockIdx.y;
  const int base = blockIdx.x * 2048;

  sKey[tid >> 3][tid & 7] = 0ull;
  for (int j = tid; j < 2048; j += 512) hh[j] = 0ull;
  if (tid < M_N) {
    const float* t = targets + ((size_t)b * M_N + tid) * 5;
    float x1 = t[0], y1 = t[1], x2 = t[2], y2 = t[3], lab = t[4];
    sTB[tid] = make_float4(x1, y1, x2, y2);
    bool valid = lab > 0.f;
    unsigned long long mask = __ballot(valid);
    int pfx = __popcll(mask & ((1ull << tid) - 1ull));
    if (valid) {
      sBX[pfx] = make_float4(x1, y1, x2, y2);
      sBA[pfx] = (x2 - x1) * (y2 - y1);
      sBM[pfx] = tid;
    }
    if (tid == 0) sNV = (int)__popcll(mask);
  }
  __syncthreads();

  const int nv = sNV;
  float ax1[4], ay1[4], ax2[4], ay2[4], sa[4];
  float bv[4]; int bm[4];
  #pragma unroll
  for (int i = 0; i < 4; ++i) {
    float4 an = anchors[base + tid + i * 512];
    ax1[i] = an.x - an.z * 0.5f; ay1[i] = an.y - an.w * 0.5f;
    ax2[i] = an.x + an.z * 0.5f; ay2[i] = an.y + an.w * 0.5f;
    sa[i] = (ax2[i] - ax1[i]) * (ay2[i] - ay1[i]);
    bv[i] = -1.0f; bm[i] = 0;   // invalid rows (-1) never beat valid q>=0
  }
  #pragma unroll 2
  for (int j = 0; j < nv; ++j) {
    float4 t = sBX[j];
    float ta = sBA[j];
    int mm = sBM[j];
    float lb = -1.0f; int li = 0;
    #pragma unroll
    for (int i = 0; i < 4; ++i) {
      float wx = fminf(ax2[i], t.z) - fmaxf(ax1[i], t.x);
      float wy = fminf(ay2[i], t.w) - fmaxf(ay1[i], t.y);
      float inter = fmaxf(wx, 0.f) * fmaxf(wy, 0.f);
      float uni = (sa[i] + ta) - inter;
      float q = inter * __builtin_amdgcn_rcpf(uni);
      if (q > bv[i]) { bv[i] = q; bm[i] = mm; }     // strict >: np first-max
      if (q > lb) { lb = q; li = i; }
    }
    float wm = lb;
    #pragma unroll
    for (int off = 32; off; off >>= 1) wm = fmaxf(wm, __shfl_xor(wm, off));
    unsigned long long msk = __ballot(lb == wm);
    int lead = __ffsll((unsigned long long)msk) - 1;
    int wi = __shfl(li, lead);
    if (lane == 0) {
      int aw = base + wave * 64 + lead + wi * 512;
      sKey[mm][wave] = ((unsigned long long)__float_as_uint(wm) << 32) |
                       (unsigned long long)(0x7FFFFFFFu - (unsigned)aw);
    }
  }

  // Phase C: losses (pre-override)
  double lL = 0.0, lC = 0.0;
  unsigned int npc = 0;
  #pragma unroll
  for (int i = 0; i < 4; ++i) {
    const int a = base + tid + i * 512;
    const size_t g = (size_t)b * A_N + a;
    bool conf = bv[i] >= OVTH;
    float2 cp = conf_pred[g];
    float mx = fmaxf(cp.x, cp.y), mn = fminf(cp.x, cp.y);
    float lse = mx + log1pf(expf(mn - mx));
    unsigned int bits = 0u;
    if (conf) {
      float ce = lse - cp.y;
      npc++; lC += (double)ce;
      float4 t = sTB[bm[i]];
      float4 an = anchors[a];
      float gx = ((t.x + t.z) * 0.5f - an.x) / (VAR0 * an.z);
      float gy = ((t.y + t.w) * 0.5f - an.y) / (VAR0 * an.w);
      float2 lp = loc_pred[g];
      lL += (double)(sl1(fabsf(lp.x - gx)) + sl1(fabsf(lp.y - gy)));
    } else {
      float ce = lse - cp.x;
      bits = __float_as_uint(ce);    // ce > 0 -> monotone, nonzero
      atomicAdd(&hh[bits >> 21], packCE(ce));
    }
    ceBits[g] = bits;
    matchOut[g] = (unsigned char)((conf ? 0x80 : 0) | bm[i]);
  }
  __syncthreads();

  // Phase D: flushes
  for (int j = tid; j < 2048; j += 512) {
    unsigned long long v = hh[j];
    if (v) atomicAdd(&h1[(size_t)b * 2048 + j], v);
  }
  if (tid < M_N) {
    unsigned long long k0 = sKey[tid][0];
    #pragma unroll
    for (int w = 1; w < 8; ++w) {
      unsigned long long k2 = sKey[tid][w];
      k0 = (k2 > k0) ? k2 : k0;
    }
    if (k0) atomicMax(bpi + b * M_N + tid, k0);
  }
  for (int off = 32; off; off >>= 1) {
    lL += __shfl_down(lL, off);
    lC += __shfl_down(lC, off);
    npc += __shfl_down(npc, off);
  }
  if (lane == 0) { rL[wave] = lL; rC[wave] = lC; rN[wave] = npc; }
  __syncthreads();
  if (tid == 0) {
    double aL = 0, aC = 0; unsigned int n = 0;
    #pragma unroll
    for (int w = 0; w < 8; ++w) { aL += rL[w]; aC += rC[w]; n += rN[w]; }
    if (aL != 0.0) atomicAdd(lossL, aL);
    if (aC != 0.0) atomicAdd(lossCp, aC);
    if (n) atomicAdd(numpos + b, n);
  }
}

// ---------------------------------------------------------------- fixup pass
// 1 block, 512 threads = one per (b,m). Dedupe: for duplicate forced anchors
// within a batch, max m wins (= numpy sequential last-write). Winner patches:
//  oldConf==0: remove neg-CE from h1 (u64 2's-complement add), ceBits=0,
//              add pos-CE, numpos++, add loc loss.
//  oldConf==1: CE unchanged (pos CE is idx-independent); adjust loc loss if
//              the matched truth changed.
__launch_bounds__(512)
__global__ void k_fix(const float4* __restrict__ anchors,
                      const float*  __restrict__ targets,
                      const float2* __restrict__ loc_pred,
                      const float2* __restrict__ conf_pred,
                      unsigned long long* __restrict__ ws64,
                      const unsigned char* __restrict__ matchOut,
                      unsigned int* __restrict__ ceBits)
{
  double* lossL  = (double*)(ws64 + 0);
  double* lossCp = (double*)(ws64 + 1);
  unsigned int* numpos = (unsigned int*)(ws64 + 2);
  const unsigned long long* bpi = ws64 + W_BPI;
  unsigned long long* h1 = ws64 + W_H1;

  __shared__ int sA[512];
  __shared__ float4 sBXf[512];
  const int tid = threadIdx.x;
  const int b = tid >> 6, m = tid & 63;
  const float* t = targets + (size_t)tid * 5;
  float4 box = make_float4(t[0], t[1], t[2], t[3]);
  bool valid = t[4] > 0.f;
  unsigned long long key = bpi[tid];
  int a = valid ? (int)(0x7FFFFFFFu - (unsigned)(key & 0xFFFFFFFFull)) : -1;
  sA[tid] = a;
  sBXf[tid] = box;
  __syncthreads();
  bool winner = (a >= 0);
  if (winner) {
    for (int m2 = m + 1; m2 < M_N; ++m2)
      if (sA[(b << 6) | m2] == a) { winner = false; break; }
  }
  if (winner) {
    const size_t g = (size_t)b * A_N + a;
    unsigned char mb = matchOut[g];
    float2 cp = conf_pred[g];
    float mx = fmaxf(cp.x, cp.y), mn = fminf(cp.x, cp.y);
    float lse = mx + log1pf(expf(mn - mx));
    float4 an = anchors[a];
    float2 lp = loc_pred[g];
    float gx = ((box.x + box.z) * 0.5f - an.x) / (VAR0 * an.z);
    float gy = ((box.y + box.w) * 0.5f - an.y) / (VAR0 * an.w);
    float newL = sl1(fabsf(lp.x - gx)) + sl1(fabsf(lp.y - gy));
    if (!(mb & 0x80)) {
      float ceN = lse - cp.x;
      unsigned int bits = __float_as_uint(ceN);
      atomicAdd(&h1[(size_t)b * 2048 + (bits >> 21)],
                (unsigned long long)(0ull - packCE(ceN)));
      ceBits[g] = 0u;
      atomicAdd(lossCp, (double)(lse - cp.y));
      atomicAdd(&numpos[b], 1u);
      atomicAdd(lossL, (double)newL);
    } else {
      int oldIdx = mb & 63;
      if (oldIdx != m) {
        float4 ob = sBXf[(b << 6) | oldIdx];
        float ox = ((ob.x + ob.z) * 0.5f - an.x) / (VAR0 * an.z);
        float oy = ((ob.y + ob.w) * 0.5f - an.y) / (VAR0 * an.w);
        float oldL = sl1(fabsf(lp.x - ox)) + sl1(fabsf(lp.y - oy));
        atomicAdd(lossL, (double)(newL - oldL));
      }
    }
  }
}

// ------------------------------------------------- radix-select helper (256t)
template <int PER>
__device__ void findBinP(const unsigned long long* __restrict__ h,
                         unsigned int k, unsigned int* scanBuf,
                         int* outT, unsigned int* outAb)
{
  const int tid = threadIdx.x;
  unsigned int c[PER];
  unsigned int ps = 0;
  #pragma unroll
  for (int j = 0; j < PER; ++j) {
    c[j] = (unsigned int)(h[tid * PER + j] >> CNT_SH);
    ps += c[j];
  }
  scanBuf[tid] = ps;
  __syncthreads();
  unsigned int v = ps;
  for (int off = 1; off < 256; off <<= 1) {
    unsigned int u = (tid + off < 256) ? scanBuf[tid + off] : 0u;
    __syncthreads();
    v += u;
    scanBuf[tid] = v;
    __syncthreads();
  }
  unsigned int above = v - ps;
  #pragma unroll
  for (int j = PER - 1; j >= 0; --j) {
    unsigned int cj = c[j];
    if (above < k && above + cj >= k) { *outT = tid * PER + j; *outAb = above; }
    above += cj;
  }
  __syncthreads();
}

// ----------------------------------------------------------- level-2 histogram
__launch_bounds__(256)
__global__ void k_sel2(const unsigned int* __restrict__ ceBits,
                       unsigned long long* __restrict__ ws64)
{
  const unsigned int* numpos = (const unsigned int*)(ws64 + 2);
  const unsigned long long* h1 = ws64 + W_H1;
  unsigned long long* h2 = ws64 + W_H2;
  __shared__ unsigned int scanBuf[256];
  __shared__ int sT; __shared__ unsigned int sAb;
  __shared__ unsigned long long hh[2048];
  const int b = blockIdx.y;
  const unsigned int P = numpos[b];
  const unsigned int k = min(3u * P, (unsigned)A_N - P);
  if (k == 0u) return;
  const int tid = threadIdx.x;
  findBinP<8>(h1 + (size_t)b * 2048, k, scanBuf, &sT, &sAb);
  const int t1 = sT;
  for (int j = tid; j < 2048; j += 256) hh[j] = 0ull;
  __syncthreads();
  const uint4* cb = (const uint4*)(ceBits + (size_t)b * A_N + blockIdx.x * 4096);
  for (int i = 0; i < 4; ++i) {
    uint4 v = cb[i * 256 + tid];
    unsigned int xs[4] = {v.x, v.y, v.z, v.w};
    #pragma unroll
    for (int c = 0; c < 4; ++c) {
      unsigned int x = xs[c];
      if (x && (int)(x >> 21) == t1)
        atomicAdd(&hh[(x >> 10) & 2047], packCE(__uint_as_float(x)));
    }
  }
  __syncthreads();
  for (int j = tid; j < 2048; j += 256) {
    unsigned long long v = hh[j];
    if (v) atomicAdd(&h2[(size_t)b * 2048 + j], v);
  }
}

// --------------------------------------------------------------- final combine
// 8 blocks; 2-level select + residual once (R6-proven, absmax 0.0).
__launch_bounds__(256)
__global__ void k_final(unsigned long long* __restrict__ ws64,
                        float* __restrict__ out)
{
  const double* lossL  = (const double*)(ws64 + 0);
  const double* lossCp = (const double*)(ws64 + 1);
  const unsigned int* numpos = (const unsigned int*)(ws64 + 2);
  double* lossCn = (double*)(ws64 + 6);
  unsigned int* ticket = (unsigned int*)(ws64 + 7);
  const unsigned long long* h1 = ws64 + W_H1;
  const unsigned long long* h2 = ws64 + W_H2;
  __shared__ unsigned int scanBuf[256];
  __shared__ int sT; __shared__ unsigned int sAb;
  __shared__ double lred[4];
  const int b = blockIdx.x;
  const int tid = threadIdx.x;
  const unsigned int P = numpos[b];
  const unsigned int k = min(3u * P, (unsigned)A_N - P);
  if (k > 0u) {
    findBinP<8>(h1 + (size_t)b * 2048, k, scanBuf, &sT, &sAb);
    const int t1 = sT; const unsigned int k1 = k - sAb;
    findBinP<8>(h2 + (size_t)b * 2048, k1, scanBuf, &sT, &sAb);
    const int t2 = sT; const unsigned int k2 = k1 - sAb;
    double sfix = 0.0;
    for (int j = tid; j < 2048; j += 256) {
      if (j > t1) sfix += (double)(h1[(size_t)b * 2048 + j] & SUM_MASK);
      if (j > t2) sfix += (double)(h2[(size_t)b * 2048 + j] & SUM_MASK);
    }
    double s = sfix * INV_FIX;
    const int lane = tid & 63, wave = tid >> 6;
    for (int off = 32; off; off >>= 1) s += __shfl_down(s, off);
    if (lane == 0) lred[wave] = s;
    __syncthreads();
    if (tid == 0) {
      double tot = lred[0] + lred[1] + lred[2] + lred[3];
      tot += (double)k2 * (double)__uint_as_float(
                 (((unsigned)t1 << 21) | ((unsigned)t2 << 10)));
      atomicAdd(lossCn, tot);
    }
  }
  __threadfence();
  if (tid == 0) {
    unsigned int tk = atomicAdd(ticket, 1u);
    if (tk == B_N - 1) {
      double lcn = atomicAdd(lossCn, 0.0);
      double ll = *lossL, lcp = *lossCp;
      unsigned int tot = 0;
      #pragma unroll
      for (int i = 0; i < B_N; ++i) tot += numpos[i];
      double tn = (double)tot;
      out[0] = (float)(ll / tn);
      out[1] = (float)((lcp + lcn) / tn);
    }
  }
}

// -------------------------------------------------------------------- launcher
extern "C" void kernel_launch(void* const* d_in, const int* in_sizes, int n_in,
                              void* d_out, int out_size, void* d_ws, size_t ws_size,
                              hipStream_t stream)
{
  const float2* loc     = (const float2*)d_in[0];  // (B,A,2)
  const float2* confp   = (const float2*)d_in[1];  // (B,A,2)
  const float4* anchors = (const float4*)d_in[2];  // (A,4)
  const float*  targets = (const float*)d_in[3];   // (B,M,5)
  char* ws = (char*)d_ws;
  unsigned long long* ws64 = (unsigned long long*)d_ws;
  unsigned char* matchOut = (unsigned char*)(ws + ZBYTES);          // [B*A] u8
  unsigned int* ceBits = (unsigned int*)(ws + ZBYTES + 1048576);    // [B*A] u32

  hipMemsetAsync(d_ws, 0, ZBYTES, stream);
  k_match<<<dim3(64, 8), 512, 0, stream>>>(anchors, targets, loc, confp,
                                           ws64, matchOut, ceBits);
  k_fix<<<1, 512, 0, stream>>>(anchors, targets, loc, confp, ws64,
                               matchOut, ceBits);
  k_sel2<<<dim3(32, 8), 256, 0, stream>>>(ceBits, ws64);
  k_final<<<8, 256, 0, stream>>>(ws64, (float*)d_out);
}